// Round 21
// baseline (79.417 us; speedup 1.0000x reference)
//
#include <hip/hip_runtime.h>
#include <hip/hip_bf16.h>
#include <stdint.h>

#define B_ 4
#define N_ 2048
#define DIM_ 512
#define H_ 8
#define D_ 64
#define M_ (B_*N_)   // 8192

typedef unsigned short u16;
typedef short bf16x8 __attribute__((ext_vector_type(8)));
typedef float f32x4 __attribute__((ext_vector_type(4)));
typedef float f32x16 __attribute__((ext_vector_type(16)));
typedef unsigned short u16x8 __attribute__((ext_vector_type(8)));
typedef unsigned short u16x4 __attribute__((ext_vector_type(4)));

__device__ __forceinline__ u16 f2bf(float f) {
  union { float f; uint32_t u; } v; v.f = f;
  uint32_t r = v.u + 0x7fffu + ((v.u >> 16) & 1u);
  return (u16)(r >> 16);
}

__device__ __forceinline__ void gload_lds16(const void* g, void* l) {
  __builtin_amdgcn_global_load_lds(
      (const __attribute__((address_space(1))) void*)g,
      (__attribute__((address_space(3))) void*)l, 16, 0, 0);
}

__device__ __forceinline__ uint32_t cvt_pk(float a, float b) {
  uint32_t r;
  asm("v_cvt_pk_bf16_f32 %0, %1, %2" : "=v"(r) : "v"(a), "v"(b));
  return r;
}

// swaps upper 32 lanes of a with lower 32 lanes of b
__device__ __forceinline__ void swap32(uint32_t &a, uint32_t &b) {
  asm("v_permlane32_swap_b32 %0, %1" : "+v"(a), "+v"(b));
}

__device__ __forceinline__ bf16x8 mkfrag(uint32_t w0, uint32_t w1, uint32_t w2, uint32_t w3) {
  union { uint32_t u[4]; bf16x8 v; } x;
  x.u[0]=w0; x.u[1]=w1; x.u[2]=w2; x.u[3]=w3;
  return x.v;
}

// ---------------- fused prep (1D grid): blocks 0..1023 = x->xb + x->vtp; 1024..1279 = W->bf16 ----------------
__global__ __launch_bounds__(256) void k_prep_x(const float* __restrict__ x,
                                                u16* __restrict__ xb,
                                                u16* __restrict__ vtp,
                                                const float* __restrict__ Wq,
                                                const float* __restrict__ Wk,
                                                u16* __restrict__ wqb,
                                                u16* __restrict__ wkb) {
  __shared__ float ts[64][65];
  int bid = blockIdx.x;
  int t = threadIdx.x;
  if (bid >= 1024) {
    int tt = (bid - 1024) * 256 + t;
    int e = tt * 8;
    const float* src; u16* dst; int off;
    if (e < DIM_*DIM_) { src = Wq; dst = wqb; off = e; }
    else               { src = Wk; dst = wkb; off = e - DIM_*DIM_; }
    const float4* p = (const float4*)(src + off);
    float4 a = p[0], b = p[1];
    u16x8 o;
    o[0]=f2bf(a.x); o[1]=f2bf(a.y); o[2]=f2bf(a.z); o[3]=f2bf(a.w);
    o[4]=f2bf(b.x); o[5]=f2bf(b.y); o[6]=f2bf(b.z); o[7]=f2bf(b.w);
    *(u16x8*)(dst + off) = o;
    return;
  }
  int nt = bid & 31;          // 0..31  (n tile of 64)
  int h  = (bid >> 5) & 7;    // 0..7
  int b  = bid >> 8;          // 0..3
  int n0 = nt * 64;
  int r16 = t >> 4;         // 0..15
  int c4  = (t & 15) * 4;   // 0..60
#pragma unroll
  for (int rep = 0; rep < 4; ++rep) {
    int n_loc = rep*16 + r16;
    size_t row = (size_t)(b*N_ + n0 + n_loc);
    float4 v = *(const float4*)(x + row*DIM_ + h*64 + c4);
    ts[n_loc][c4+0]=v.x; ts[n_loc][c4+1]=v.y; ts[n_loc][c4+2]=v.z; ts[n_loc][c4+3]=v.w;
    u16x4 o; o[0]=f2bf(v.x); o[1]=f2bf(v.y); o[2]=f2bf(v.z); o[3]=f2bf(v.w);
    *(u16x4*)(xb + row*DIM_ + h*64 + c4) = o;
  }
  __syncthreads();
  u16* vb_ = vtp + (size_t)(b*H_+h)*131072 + (size_t)(nt*8)*512;
#pragma unroll
  for (int rep = 0; rep < 2; ++rep) {
    int c = rep*256 + t;       // 0..511
    int g = c >> 6;            // 0..7  (n sub-block of 8)
    int d = c & 63;            // 0..63
    u16x8 o;
#pragma unroll
    for (int j = 0; j < 8; ++j) o[j] = f2bf(ts[g*8 + j][d]);
    *(u16x8*)(vb_ + (size_t)g*512 + d*8) = o;   // fully coalesced
  }
}

// ---------------- colsum V (coalesced u16x8, deterministic) ----------------
__global__ __launch_bounds__(512) void k_misc(const u16* __restrict__ vtp,
                                              float* __restrict__ Sv) {
  __shared__ float red2[8][64];
  int bh = blockIdx.x;
  int t = threadIdx.x;
  int d = t & 63, g0 = t >> 6;   // g0 0..7
  const u16* base = vtp + (size_t)bh*131072 + (size_t)d*8;
  float s = 0.f;
  for (int i = 0; i < 32; ++i) {
    u16x8 v = *(const u16x8*)(base + (size_t)(g0 + i*8)*512);
#pragma unroll
    for (int j = 0; j < 8; ++j) {
      union { uint32_t u; float f; } cv; cv.u = (uint32_t)v[j] << 16;
      s += cv.f;
    }
  }
  red2[g0][d] = s;
  __syncthreads();
  if (t < 64) {
    float acc = 0.f;
#pragma unroll
    for (int i = 0; i < 8; ++i) acc += red2[i][t];
    Sv[bh*64 + t] = acc;
  }
}

// ---------------- projection GEMM (2-phase dbuf, 8 waves): q/k [bh][d>>3][n][d&7] ----------------
__global__ __launch_bounds__(512, 4) void k_gemm_qk(const u16* __restrict__ xb,
                                                    const u16* __restrict__ wqb,
                                                    const u16* __restrict__ wkb,
                                                    u16* __restrict__ qbp,
                                                    u16* __restrict__ kbp) {
  __shared__ __align__(16) u16 As[2][128*64];
  __shared__ __align__(16) u16 Bs[2][128*64];
  int mt = blockIdx.x, ntile = blockIdx.y, z = blockIdx.z;
  const u16* Bw = z ? wkb : wqb;
  u16* C = z ? kbp : qbp;
  float scale = z ? 1.0f : 0.36067376022224085f;   // 0.125 * 2.8853900817779268
  int tid = threadIdx.x, lane = tid & 63, w = tid >> 6;   // w 0..7
  int wr = w >> 2, wc = w & 3;                            // 2 x 4
  int lr = lane >> 3, lc8 = lane & 7;
  int l4 = lane >> 4, l15 = lane & 15;

  f32x4 acc[4][2] = {};

  const u16* Abase = xb + (size_t)(mt*128)*DIM_;
  const u16* Bbase = Bw + (size_t)(ntile*128)*DIM_;

#define GSTAGE(buf, kk_) do { \
    _Pragma("unroll") \
    for (int i_ = 0; i_ < 2; ++i_) { \
      int rowl_ = w*16 + i_*8 + lr; \
      int cbs_ = lc8 ^ (rowl_ & 7); \
      gload_lds16(Abase + (size_t)rowl_*DIM_ + (kk_)*64 + cbs_*8, As[buf] + (w*16 + i_*8)*64); \
      gload_lds16(Bbase + (size_t)rowl_*DIM_ + (kk_)*64 + cbs_*8, Bs[buf] + (w*16 + i_*8)*64); \
    } \
  } while (0)

  GSTAGE(0, 0);
  __syncthreads();

  for (int kk = 0; kk < 8; ++kk) {
    int cur = kk & 1;
    if (kk < 7) GSTAGE(cur ^ 1, kk + 1);
#pragma unroll
    for (int kc = 0; kc < 2; ++kc) {
      bf16x8 af[4], bfr[2];
#pragma unroll
      for (int i = 0; i < 4; ++i) {
        int row = wr*64 + i*16 + l15;
        int cb = (kc*4 + l4) ^ (row & 7);
        af[i] = *(const bf16x8*)(As[cur] + row*64 + cb*8);
      }
#pragma unroll
      for (int j = 0; j < 2; ++j) {
        int row = wc*32 + j*16 + l15;
        int cb = (kc*4 + l4) ^ (row & 7);
        bfr[j] = *(const bf16x8*)(Bs[cur] + row*64 + cb*8);
      }
      // swapped: row-dim = W feature, col-dim = token
#pragma unroll
      for (int i = 0; i < 4; ++i)
#pragma unroll
        for (int j = 0; j < 2; ++j)
          acc[i][j] = __builtin_amdgcn_mfma_f32_16x16x32_bf16(bfr[j], af[i], acc[i][j], 0, 0, 0);
    }
    __syncthreads();
  }
#undef GSTAGE
  // store: token tk lane-indexed, feature reg-indexed -> u16x4 (coalesced)
#pragma unroll
  for (int i = 0; i < 4; ++i) {
    int tk = mt*128 + wr*64 + i*16 + l15;
    int b_ = tk >> 11, n_ = tk & (N_-1);
#pragma unroll
    for (int j = 0; j < 2; ++j) {
      int of0 = ntile*128 + wc*32 + j*16 + l4*4;
      int h_ = of0 >> 6, d0 = of0 & 63;
      u16x4 o;
#pragma unroll
      for (int r = 0; r < 4; ++r) o[r] = f2bf(acc[i][j][r] * scale);
      *(u16x4*)(C + (size_t)(b_*H_ + h_)*131072 + (size_t)(d0 >> 3)*16384
                  + (size_t)n_*8 + (d0 & 7)) = o;
    }
  }
}

// ---------------- attention: out = tanh(q k^T) v  (single-state rotation, LDS-free) ----------------
// grid 512 blocks (xcd-chunked), 512 threads = 8 waves = 4 qsub x 2 kv-half.
// Rotated pipeline: pa=tanhpack(st); st=QK(jt+1); PV(jt) -- QK(jt+1) issues
// BEFORE PV(jt)'s MFMAs, so its chain completes under them; tanh(jt+1) does not
// stall. Single st/ka/vb state -> ~114 live regs, no spill at (512,4).
__global__ __launch_bounds__(512, 4) void k_attn(const u16* __restrict__ qbp,
                                                 const u16* __restrict__ kbp,
                                                 const u16* __restrict__ vtp,
                                                 const float* __restrict__ Sv,
                                                 float* __restrict__ out) {
  __shared__ float red[4][32][64];   // 32 KB, epilogue reduce only
  int wg = blockIdx.x;
  int xcd = wg & 7, local = wg >> 3;       // local 0..63
  int bh = (xcd << 2) | (local >> 4);      // 4 bh per XCD -> K/V L2-resident
  int qt = local & 15;                     // 0..15, 128 q rows
  int tid = threadIdx.x, lane = tid & 63, w = tid >> 6;   // w 0..7
  int w4 = w & 3, grp = w >> 2;            // q sub-tile / kv half
  int l31 = lane & 31, hi = lane >> 5;
  int qrow = qt*128 + w4*32 + l31;

  // Q fragments from fragment-native qbp (coalesced)
  const u16* qp = qbp + (size_t)bh*131072 + (size_t)qrow*8;
  bf16x8 qf[4];
#pragma unroll
  for (int c = 0; c < 4; ++c) qf[c] = *(const bf16x8*)(qp + (size_t)(c*2 + hi)*16384);

  int kvb = grp * 1024;
  const u16* kp = kbp + (size_t)bh*131072 + (size_t)hi*16384 + (size_t)(kvb + l31)*8;
  const u16* vp = vtp + (size_t)bh*131072 + (size_t)((kvb >> 3) + hi)*512 + (size_t)l31*8;

  const f32x16 zz = {};
  f32x16 acc_o0 = {};
  f32x16 acc_o1 = {};

  bf16x8 ka[4];
  bf16x8 vb[2][2];
#pragma unroll
  for (int c = 0; c < 4; ++c)
    ka[c] = *(const bf16x8*)(kp + c*32768);
#pragma unroll
  for (int kc = 0; kc < 2; ++kc)
#pragma unroll
    for (int dh = 0; dh < 2; ++dh)
      vb[kc][dh] = *(const bf16x8*)(vp + kc*1024 + dh*256);

  // prologue: st = QK(tile 0); load ka <- tile 1
  __builtin_amdgcn_s_setprio(1);
  f32x16 st = __builtin_amdgcn_mfma_f32_32x32x16_bf16(ka[0], qf[0], zz, 0, 0, 0);
  st = __builtin_amdgcn_mfma_f32_32x32x16_bf16(ka[1], qf[1], st, 0, 0, 0);
  st = __builtin_amdgcn_mfma_f32_32x32x16_bf16(ka[2], qf[2], st, 0, 0, 0);
  st = __builtin_amdgcn_mfma_f32_32x32x16_bf16(ka[3], qf[3], st, 0, 0, 0);
  __builtin_amdgcn_s_setprio(0);
#pragma unroll
  for (int c = 0; c < 4; ++c)
    ka[c] = *(const bf16x8*)(kp + 256 + c*32768);

  for (int jt = 0; jt < 32; ++jt) {
    // 1. tanh+pack st(jt) -> pa  (st dead after)
    float p[16];
#pragma unroll
    for (int r = 0; r < 16; ++r) {
      float e = __builtin_amdgcn_exp2f(st[r]);
      p[r] = __builtin_amdgcn_rcpf(e + 1.0f);
    }
    uint32_t a0 = cvt_pk(p[0], p[1]),   b0 = cvt_pk(p[4], p[5]);
    uint32_t a1 = cvt_pk(p[2], p[3]),   b1 = cvt_pk(p[6], p[7]);
    swap32(a0, b0); swap32(a1, b1);
    uint32_t a2 = cvt_pk(p[8], p[9]),   b2 = cvt_pk(p[12], p[13]);
    uint32_t a3 = cvt_pk(p[10], p[11]), b3 = cvt_pk(p[14], p[15]);
    swap32(a2, b2); swap32(a3, b3);
    bf16x8 pa0 = mkfrag(a0, a1, b0, b1);   // kv 0..15
    bf16x8 pa1 = mkfrag(a2, a3, b2, b3);   // kv 16..31
    // 2. st = QK(jt+1) (issues before PV; completes under PV's MFMAs)
    if (jt < 31) {
      __builtin_amdgcn_s_setprio(1);
      st = __builtin_amdgcn_mfma_f32_32x32x16_bf16(ka[0], qf[0], zz, 0, 0, 0);
      st = __builtin_amdgcn_mfma_f32_32x32x16_bf16(ka[1], qf[1], st, 0, 0, 0);
      st = __builtin_amdgcn_mfma_f32_32x32x16_bf16(ka[2], qf[2], st, 0, 0, 0);
      st = __builtin_amdgcn_mfma_f32_32x32x16_bf16(ka[3], qf[3], st, 0, 0, 0);
      __builtin_amdgcn_s_setprio(0);
    }
    // 3. prefetch ka <- jt+2
    if (jt < 30) {
#pragma unroll
      for (int c = 0; c < 4; ++c)
        ka[c] = *(const bf16x8*)(kp + (jt+2)*256 + c*32768);
    }
    // 4. PV(jt)
    __builtin_amdgcn_s_setprio(1);
    acc_o0 = __builtin_amdgcn_mfma_f32_32x32x16_bf16(pa0, vb[0][0], acc_o0, 0, 0, 0);
    acc_o1 = __builtin_amdgcn_mfma_f32_32x32x16_bf16(pa0, vb[0][1], acc_o1, 0, 0, 0);
    acc_o0 = __builtin_amdgcn_mfma_f32_32x32x16_bf16(pa1, vb[1][0], acc_o0, 0, 0, 0);
    acc_o1 = __builtin_amdgcn_mfma_f32_32x32x16_bf16(pa1, vb[1][1], acc_o1, 0, 0, 0);
    __builtin_amdgcn_s_setprio(0);
    // 5. load vb <- jt+1
    if (jt < 31) {
#pragma unroll
      for (int kc = 0; kc < 2; ++kc)
#pragma unroll
        for (int dh = 0; dh < 2; ++dh)
          vb[kc][dh] = *(const bf16x8*)(vp + (jt+1)*2048 + kc*1024 + dh*256);
    }
  }

  // 2-way kv combine via LDS, then O = Sv - 2*acc
  if (grp == 1) {
#pragma unroll
    for (int r = 0; r < 16; ++r) {
      int row = 4*hi + (r & 3) + 8*(r >> 2);
      red[w4][row][l31]      = acc_o0[r];
      red[w4][row][l31 + 32] = acc_o1[r];
    }
  }
  __syncthreads();
  if (grp == 0) {
    int b = bh >> 3, h = bh & 7;
    int q0 = qt*128 + w4*32 + 4*hi;
    float sv0 = Sv[bh*64 + l31];
    float sv1 = Sv[bh*64 + 32 + l31];
    float* ob = out + (size_t)b*N_*DIM_ + h*64 + l31;
#pragma unroll
    for (int r = 0; r < 16; ++r) {
      int row = 4*hi + (r & 3) + 8*(r >> 2);
      int q = q0 + (r & 3) + 8*(r >> 2);
      ob[(size_t)q*DIM_]      = fmaf(-2.0f, acc_o0[r] + red[w4][row][l31],      sv0);
      ob[(size_t)q*DIM_ + 32] = fmaf(-2.0f, acc_o1[r] + red[w4][row][l31 + 32], sv1);
    }
  }
}

extern "C" void kernel_launch(void* const* d_in, const int* in_sizes, int n_in,
                              void* d_out, int out_size, void* d_ws, size_t ws_size,
                              hipStream_t stream) {
  const float* x  = (const float*)d_in[0];
  const float* Wq = (const float*)d_in[1];
  const float* Wk = (const float*)d_in[2];
  float* out = (float*)d_out;
  char* ws = (char*)d_ws;
  u16* xb  = (u16*)(ws);                      // 8 MiB
  u16* wqb = (u16*)(ws + 8388608);            // 512 KiB
  u16* wkb = (u16*)(ws + 8912896);            // 512 KiB
  u16* qbp = (u16*)(ws + 9437184);            // 8 MiB  [bh][d>>3][n][d&7]
  u16* kbp = (u16*)(ws + 17825792);           // 8 MiB  [bh][d>>3][kv][d&7]
  u16* vtp = (u16*)(ws + 26214400);           // 8 MiB  [bh][kv>>3][d][kv&7]
  float* Sv = (float*)(ws + 34603008);        // 8 KiB  [bh][d]

  k_prep_x<<<1280, 256, 0, stream>>>(x, xb, vtp, Wq, Wk, wqb, wkb);
  k_misc<<<32, 512, 0, stream>>>(vtp, Sv);
  k_gemm_qk<<<dim3(64, 4, 2), 512, 0, stream>>>(xb, wqb, wkb, qbp, kbp);
  k_attn<<<512, 512, 0, stream>>>(qbp, kbp, vtp, Sv, out);
}

// Round 22
// 76.602 us; speedup vs baseline: 1.0367x; 1.0367x over previous
//
#include <hip/hip_runtime.h>
#include <hip/hip_bf16.h>
#include <stdint.h>

#define B_ 4
#define N_ 2048
#define DIM_ 512
#define H_ 8
#define D_ 64
#define M_ (B_*N_)   // 8192

typedef unsigned short u16;
typedef short bf16x8 __attribute__((ext_vector_type(8)));
typedef float f32x4 __attribute__((ext_vector_type(4)));
typedef float f32x16 __attribute__((ext_vector_type(16)));
typedef unsigned short u16x8 __attribute__((ext_vector_type(8)));
typedef unsigned short u16x4 __attribute__((ext_vector_type(4)));

__device__ __forceinline__ u16 f2bf(float f) {
  union { float f; uint32_t u; } v; v.f = f;
  uint32_t r = v.u + 0x7fffu + ((v.u >> 16) & 1u);
  return (u16)(r >> 16);
}

__device__ __forceinline__ void gload_lds16(const void* g, void* l) {
  __builtin_amdgcn_global_load_lds(
      (const __attribute__((address_space(1))) void*)g,
      (__attribute__((address_space(3))) void*)l, 16, 0, 0);
}

__device__ __forceinline__ uint32_t cvt_pk(float a, float b) {
  uint32_t r;
  asm("v_cvt_pk_bf16_f32 %0, %1, %2" : "=v"(r) : "v"(a), "v"(b));
  return r;
}

// swaps upper 32 lanes of a with lower 32 lanes of b
__device__ __forceinline__ void swap32(uint32_t &a, uint32_t &b) {
  asm("v_permlane32_swap_b32 %0, %1" : "+v"(a), "+v"(b));
}

__device__ __forceinline__ bf16x8 mkfrag(uint32_t w0, uint32_t w1, uint32_t w2, uint32_t w3) {
  union { uint32_t u[4]; bf16x8 v; } x;
  x.u[0]=w0; x.u[1]=w1; x.u[2]=w2; x.u[3]=w3;
  return x.v;
}

// ---------------- fused prep (1D grid): blocks 0..1023 = x->xb + x->vtp; 1024..1279 = W->bf16 ----------------
__global__ __launch_bounds__(256) void k_prep_x(const float* __restrict__ x,
                                                u16* __restrict__ xb,
                                                u16* __restrict__ vtp,
                                                const float* __restrict__ Wq,
                                                const float* __restrict__ Wk,
                                                u16* __restrict__ wqb,
                                                u16* __restrict__ wkb) {
  __shared__ float ts[64][65];
  int bid = blockIdx.x;
  int t = threadIdx.x;
  if (bid >= 1024) {
    int tt = (bid - 1024) * 256 + t;
    int e = tt * 8;
    const float* src; u16* dst; int off;
    if (e < DIM_*DIM_) { src = Wq; dst = wqb; off = e; }
    else               { src = Wk; dst = wkb; off = e - DIM_*DIM_; }
    const float4* p = (const float4*)(src + off);
    float4 a = p[0], b = p[1];
    u16x8 o;
    o[0]=f2bf(a.x); o[1]=f2bf(a.y); o[2]=f2bf(a.z); o[3]=f2bf(a.w);
    o[4]=f2bf(b.x); o[5]=f2bf(b.y); o[6]=f2bf(b.z); o[7]=f2bf(b.w);
    *(u16x8*)(dst + off) = o;
    return;
  }
  int nt = bid & 31;          // 0..31  (n tile of 64)
  int h  = (bid >> 5) & 7;    // 0..7
  int b  = bid >> 8;          // 0..3
  int n0 = nt * 64;
  int r16 = t >> 4;         // 0..15
  int c4  = (t & 15) * 4;   // 0..60
#pragma unroll
  for (int rep = 0; rep < 4; ++rep) {
    int n_loc = rep*16 + r16;
    size_t row = (size_t)(b*N_ + n0 + n_loc);
    float4 v = *(const float4*)(x + row*DIM_ + h*64 + c4);
    ts[n_loc][c4+0]=v.x; ts[n_loc][c4+1]=v.y; ts[n_loc][c4+2]=v.z; ts[n_loc][c4+3]=v.w;
    u16x4 o; o[0]=f2bf(v.x); o[1]=f2bf(v.y); o[2]=f2bf(v.z); o[3]=f2bf(v.w);
    *(u16x4*)(xb + row*DIM_ + h*64 + c4) = o;
  }
  __syncthreads();
  u16* vb_ = vtp + (size_t)(b*H_+h)*131072 + (size_t)(nt*8)*512;
#pragma unroll
  for (int rep = 0; rep < 2; ++rep) {
    int c = rep*256 + t;       // 0..511
    int g = c >> 6;            // 0..7  (n sub-block of 8)
    int d = c & 63;            // 0..63
    u16x8 o;
#pragma unroll
    for (int j = 0; j < 8; ++j) o[j] = f2bf(ts[g*8 + j][d]);
    *(u16x8*)(vb_ + (size_t)g*512 + d*8) = o;   // fully coalesced
  }
}

// ---------------- GEMM (blocks 0..511) + colsum V (blocks 512..543), 1D grid ----------------
// GEMM: 2-phase dbuf, 8 waves (2Mx4N), 128x128 tile, fragment-native q/k stores.
// colsum: Sv[bh][d] = sum_kv v (coalesced u16x8, deterministic).
__global__ __launch_bounds__(512, 4) void k_gemm_qk(const u16* __restrict__ xb,
                                                    const u16* __restrict__ wqb,
                                                    const u16* __restrict__ wkb,
                                                    u16* __restrict__ qbp,
                                                    u16* __restrict__ kbp,
                                                    const u16* __restrict__ vtp,
                                                    float* __restrict__ Sv) {
  __shared__ __align__(16) u16 As[2][128*64];
  __shared__ __align__(16) u16 Bs[2][128*64];
  int bid = blockIdx.x;
  int tid = threadIdx.x;
  if (bid >= 512) {
    // ---- colsum ----
    float* red2 = (float*)&As[0][0];   // [8][64] f32, aliased onto As
    int bh = bid - 512;
    int d = tid & 63, g0 = tid >> 6;   // g0 0..7
    const u16* base = vtp + (size_t)bh*131072 + (size_t)d*8;
    float s = 0.f;
    for (int i = 0; i < 32; ++i) {
      u16x8 v = *(const u16x8*)(base + (size_t)(g0 + i*8)*512);
#pragma unroll
      for (int j = 0; j < 8; ++j) {
        union { uint32_t u; float f; } cv; cv.u = (uint32_t)v[j] << 16;
        s += cv.f;
      }
    }
    red2[g0*64 + d] = s;
    __syncthreads();
    if (tid < 64) {
      float acc = 0.f;
#pragma unroll
      for (int i = 0; i < 8; ++i) acc += red2[i*64 + tid];
      Sv[bh*64 + tid] = acc;
    }
    return;
  }
  // ---- GEMM ----
  int mt = bid & 63, ntile = (bid >> 6) & 3, z = bid >> 8;
  const u16* Bw = z ? wkb : wqb;
  u16* C = z ? kbp : qbp;
  float scale = z ? 1.0f : 0.36067376022224085f;   // 0.125 * 2.8853900817779268
  int lane = tid & 63, w = tid >> 6;   // w 0..7
  int wr = w >> 2, wc = w & 3;         // 2 x 4
  int lr = lane >> 3, lc8 = lane & 7;
  int l4 = lane >> 4, l15 = lane & 15;

  f32x4 acc[4][2] = {};

  const u16* Abase = xb + (size_t)(mt*128)*DIM_;
  const u16* Bbase = Bw + (size_t)(ntile*128)*DIM_;

#define GSTAGE(buf, kk_) do { \
    _Pragma("unroll") \
    for (int i_ = 0; i_ < 2; ++i_) { \
      int rowl_ = w*16 + i_*8 + lr; \
      int cbs_ = lc8 ^ (rowl_ & 7); \
      gload_lds16(Abase + (size_t)rowl_*DIM_ + (kk_)*64 + cbs_*8, As[buf] + (w*16 + i_*8)*64); \
      gload_lds16(Bbase + (size_t)rowl_*DIM_ + (kk_)*64 + cbs_*8, Bs[buf] + (w*16 + i_*8)*64); \
    } \
  } while (0)

  GSTAGE(0, 0);
  __syncthreads();

  for (int kk = 0; kk < 8; ++kk) {
    int cur = kk & 1;
    if (kk < 7) GSTAGE(cur ^ 1, kk + 1);
#pragma unroll
    for (int kc = 0; kc < 2; ++kc) {
      bf16x8 af[4], bfr[2];
#pragma unroll
      for (int i = 0; i < 4; ++i) {
        int row = wr*64 + i*16 + l15;
        int cb = (kc*4 + l4) ^ (row & 7);
        af[i] = *(const bf16x8*)(As[cur] + row*64 + cb*8);
      }
#pragma unroll
      for (int j = 0; j < 2; ++j) {
        int row = wc*32 + j*16 + l15;
        int cb = (kc*4 + l4) ^ (row & 7);
        bfr[j] = *(const bf16x8*)(Bs[cur] + row*64 + cb*8);
      }
      // swapped: row-dim = W feature, col-dim = token
#pragma unroll
      for (int i = 0; i < 4; ++i)
#pragma unroll
        for (int j = 0; j < 2; ++j)
          acc[i][j] = __builtin_amdgcn_mfma_f32_16x16x32_bf16(bfr[j], af[i], acc[i][j], 0, 0, 0);
    }
    __syncthreads();
  }
#undef GSTAGE
  // store: token tk lane-indexed, feature reg-indexed -> u16x4 (coalesced)
#pragma unroll
  for (int i = 0; i < 4; ++i) {
    int tk = mt*128 + wr*64 + i*16 + l15;
    int b_ = tk >> 11, n_ = tk & (N_-1);
#pragma unroll
    for (int j = 0; j < 2; ++j) {
      int of0 = ntile*128 + wc*32 + j*16 + l4*4;
      int h_ = of0 >> 6, d0 = of0 & 63;
      u16x4 o;
#pragma unroll
      for (int r = 0; r < 4; ++r) o[r] = f2bf(acc[i][j][r] * scale);
      *(u16x4*)(C + (size_t)(b_*H_ + h_)*131072 + (size_t)(d0 >> 3)*16384
                  + (size_t)n_*8 + (d0 & 7)) = o;
    }
  }
}

// ---------------- attention: out = tanh(q k^T) v  (R15 proven body, LDS-free) ----------------
// grid 512 blocks (xcd-chunked), 512 threads = 8 waves = 4 qsub x 2 kv-half.
// Fragment-native layouts -> coalesced global b128 loads (L2-resident).
// Register prefetch: K(jt+1) after QK consumes ka, V(jt+1) after PV consumes vb.
// tanh via linearity: O = Sv - 2*sum(R*v), R = rcp(exp2(s')+1).
__global__ __launch_bounds__(512, 4) void k_attn(const u16* __restrict__ qbp,
                                                 const u16* __restrict__ kbp,
                                                 const u16* __restrict__ vtp,
                                                 const float* __restrict__ Sv,
                                                 float* __restrict__ out) {
  __shared__ float red[4][32][64];   // 32 KB, epilogue reduce only
  int wg = blockIdx.x;
  int xcd = wg & 7, local = wg >> 3;       // local 0..63
  int bh = (xcd << 2) | (local >> 4);      // 4 bh per XCD -> K/V L2-resident
  int qt = local & 15;                     // 0..15, 128 q rows
  int tid = threadIdx.x, lane = tid & 63, w = tid >> 6;   // w 0..7
  int w4 = w & 3, grp = w >> 2;            // q sub-tile / kv half
  int l31 = lane & 31, hi = lane >> 5;
  int qrow = qt*128 + w4*32 + l31;

  // Q fragments from fragment-native qbp (coalesced)
  const u16* qp = qbp + (size_t)bh*131072 + (size_t)qrow*8;
  bf16x8 qf[4];
#pragma unroll
  for (int c = 0; c < 4; ++c) qf[c] = *(const bf16x8*)(qp + (size_t)(c*2 + hi)*16384);

  int kvb = grp * 1024;
  const u16* kp = kbp + (size_t)bh*131072 + (size_t)hi*16384 + (size_t)(kvb + l31)*8;
  const u16* vp = vtp + (size_t)bh*131072 + (size_t)((kvb >> 3) + hi)*512 + (size_t)l31*8;

  const f32x16 zz = {};   // loop-invariant zero C-operand
  f32x16 acc_o0 = {};
  f32x16 acc_o1 = {};

  bf16x8 ka[4];
  bf16x8 vb[2][2];
#pragma unroll
  for (int c = 0; c < 4; ++c)
    ka[c] = *(const bf16x8*)(kp + c*32768);
#pragma unroll
  for (int kc = 0; kc < 2; ++kc)
#pragma unroll
    for (int dh = 0; dh < 2; ++dh)
      vb[kc][dh] = *(const bf16x8*)(vp + kc*1024 + dh*256);

  for (int jt = 0; jt < 32; ++jt) {
    // S^T tile: rows = kv (crow(r,hi)), cols = q (l31)
    __builtin_amdgcn_s_setprio(1);
    f32x16 st = __builtin_amdgcn_mfma_f32_32x32x16_bf16(ka[0], qf[0], zz, 0, 0, 0);
    st = __builtin_amdgcn_mfma_f32_32x32x16_bf16(ka[1], qf[1], st, 0, 0, 0);
    st = __builtin_amdgcn_mfma_f32_32x32x16_bf16(ka[2], qf[2], st, 0, 0, 0);
    st = __builtin_amdgcn_mfma_f32_32x32x16_bf16(ka[3], qf[3], st, 0, 0, 0);
    __builtin_amdgcn_s_setprio(0);
    // prefetch next K (ka consumed at mfma issue; full tanh+PV phase of cover)
    if (jt < 31) {
#pragma unroll
      for (int c = 0; c < 4; ++c)
        ka[c] = *(const bf16x8*)(kp + (jt+1)*256 + c*32768);
    }
    // R = rcp(exp2(s') + 1)   (exp2+rcp on trans pipe)
    float p[16];
#pragma unroll
    for (int r = 0; r < 16; ++r) {
      float e = __builtin_amdgcn_exp2f(st[r]);
      p[r] = __builtin_amdgcn_rcpf(e + 1.0f);
    }
    // pack to PV A-fragments: word w holds kv = ks*16 + hi*8 + {2w,2w+1}
    uint32_t a0 = cvt_pk(p[0], p[1]),   b0 = cvt_pk(p[4], p[5]);
    uint32_t a1 = cvt_pk(p[2], p[3]),   b1 = cvt_pk(p[6], p[7]);
    swap32(a0, b0); swap32(a1, b1);
    uint32_t a2 = cvt_pk(p[8], p[9]),   b2 = cvt_pk(p[12], p[13]);
    uint32_t a3 = cvt_pk(p[10], p[11]), b3 = cvt_pk(p[14], p[15]);
    swap32(a2, b2); swap32(a3, b3);
    bf16x8 pa0 = mkfrag(a0, a1, b0, b1);   // kv 0..15
    bf16x8 pa1 = mkfrag(a2, a3, b2, b3);   // kv 16..31
    // acc += R V
    __builtin_amdgcn_s_setprio(1);
    acc_o0 = __builtin_amdgcn_mfma_f32_32x32x16_bf16(pa0, vb[0][0], acc_o0, 0, 0, 0);
    acc_o1 = __builtin_amdgcn_mfma_f32_32x32x16_bf16(pa0, vb[0][1], acc_o1, 0, 0, 0);
    acc_o0 = __builtin_amdgcn_mfma_f32_32x32x16_bf16(pa1, vb[1][0], acc_o0, 0, 0, 0);
    acc_o1 = __builtin_amdgcn_mfma_f32_32x32x16_bf16(pa1, vb[1][1], acc_o1, 0, 0, 0);
    __builtin_amdgcn_s_setprio(0);
    // prefetch next V (vb consumed; next QK+tanh phase of cover)
    if (jt < 31) {
#pragma unroll
      for (int kc = 0; kc < 2; ++kc)
#pragma unroll
        for (int dh = 0; dh < 2; ++dh)
          vb[kc][dh] = *(const bf16x8*)(vp + (jt+1)*2048 + kc*1024 + dh*256);
    }
  }

  // 2-way kv combine via LDS, then O = Sv - 2*acc
  if (grp == 1) {
#pragma unroll
    for (int r = 0; r < 16; ++r) {
      int row = 4*hi + (r & 3) + 8*(r >> 2);
      red[w4][row][l31]      = acc_o0[r];
      red[w4][row][l31 + 32] = acc_o1[r];
    }
  }
  __syncthreads();
  if (grp == 0) {
    int b = bh >> 3, h = bh & 7;
    int q0 = qt*128 + w4*32 + 4*hi;
    float sv0 = Sv[bh*64 + l31];
    float sv1 = Sv[bh*64 + 32 + l31];
    float* ob = out + (size_t)b*N_*DIM_ + h*64 + l31;
#pragma unroll
    for (int r = 0; r < 16; ++r) {
      int row = 4*hi + (r & 3) + 8*(r >> 2);
      int q = q0 + (r & 3) + 8*(r >> 2);
      ob[(size_t)q*DIM_]      = fmaf(-2.0f, acc_o0[r] + red[w4][row][l31],      sv0);
      ob[(size_t)q*DIM_ + 32] = fmaf(-2.0f, acc_o1[r] + red[w4][row][l31 + 32], sv1);
    }
  }
}

extern "C" void kernel_launch(void* const* d_in, const int* in_sizes, int n_in,
                              void* d_out, int out_size, void* d_ws, size_t ws_size,
                              hipStream_t stream) {
  const float* x  = (const float*)d_in[0];
  const float* Wq = (const float*)d_in[1];
  const float* Wk = (const float*)d_in[2];
  float* out = (float*)d_out;
  char* ws = (char*)d_ws;
  u16* xb  = (u16*)(ws);                      // 8 MiB
  u16* wqb = (u16*)(ws + 8388608);            // 512 KiB
  u16* wkb = (u16*)(ws + 8912896);            // 512 KiB
  u16* qbp = (u16*)(ws + 9437184);            // 8 MiB  [bh][d>>3][n][d&7]
  u16* kbp = (u16*)(ws + 17825792);           // 8 MiB  [bh][d>>3][kv][d&7]
  u16* vtp = (u16*)(ws + 26214400);           // 8 MiB  [bh][kv>>3][d][kv&7]
  float* Sv = (float*)(ws + 34603008);        // 8 KiB  [bh][d]

  k_prep_x<<<1280, 256, 0, stream>>>(x, xb, vtp, Wq, Wk, wqb, wkb);
  k_gemm_qk<<<544, 512, 0, stream>>>(xb, wqb, wkb, qbp, kbp, vtp, Sv);
  k_attn<<<512, 512, 0, stream>>>(qbp, kbp, vtp, Sv, out);
}